// Round 3
// baseline (380.367 us; speedup 1.0000x reference)
//
#include <hip/hip_runtime.h>
#include <hip/hip_bf16.h>

typedef __attribute__((ext_vector_type(8))) short short8;
typedef __attribute__((ext_vector_type(4))) float f32x4;

__device__ __forceinline__ float bf2f(unsigned short u) {
    unsigned int v = ((unsigned int)u) << 16;
    float f;
    __builtin_memcpy(&f, &v, 4);
    return f;
}
__device__ __forceinline__ unsigned short f2bf(float f) {
    __hip_bfloat16 h = __float2bfloat16(f);
    unsigned short u;
    __builtin_memcpy(&u, &h, 2);
    return u;
}

// ---------------------------------------------------------------------------
// Weight transpose + f32->bf16: WT[n][k] = bf16(W[k][n]), 1024x1024, 4 mats.
// ---------------------------------------------------------------------------
__global__ __launch_bounds__(256) void transpose_w(
    const float* __restrict__ W0, const float* __restrict__ W1,
    const float* __restrict__ W2, const float* __restrict__ W3,
    unsigned short* __restrict__ T0, unsigned short* __restrict__ T1,
    unsigned short* __restrict__ T2, unsigned short* __restrict__ T3)
{
    __shared__ unsigned short Ts[64 * 72];
    const float* W;
    unsigned short* T;
    switch (blockIdx.z) {
        case 0: W = W0; T = T0; break;
        case 1: W = W1; T = T1; break;
        case 2: W = W2; T = T2; break;
        default: W = W3; T = T3; break;
    }
    int tid = threadIdx.x;
    int c = tid & 7, r = tid >> 3;               // c: 8-elem chunk, r: 0..31
    int k0 = blockIdx.x * 64, n0 = blockIdx.y * 64;
    for (int i = 0; i < 64; i += 32) {
        const float* src = &W[(size_t)(k0 + r + i) * 1024 + n0 + c * 8];
        float4 x0 = *(const float4*)src;
        float4 x1 = *(const float4*)(src + 4);
        unsigned short* d = &Ts[(r + i) * 72 + c * 8];
        d[0] = f2bf(x0.x); d[1] = f2bf(x0.y); d[2] = f2bf(x0.z); d[3] = f2bf(x0.w);
        d[4] = f2bf(x1.x); d[5] = f2bf(x1.y); d[6] = f2bf(x1.z); d[7] = f2bf(x1.w);
    }
    __syncthreads();
    for (int i = 0; i < 64; i += 32) {
        union { unsigned short s[8]; uint4 v; } u;
        for (int j = 0; j < 8; j++) u.s[j] = Ts[(c * 8 + j) * 72 + (r + i)];
        *(uint4*)&T[(size_t)(n0 + r + i) * 1024 + k0 + c * 8] = u.v;
    }
}

// ---------------------------------------------------------------------------
// Vh [bh][2048][64] -> VhT [bh][64][2048]  (bf16 ws -> bf16 ws)
// ---------------------------------------------------------------------------
__global__ __launch_bounds__(256) void transpose_v(
    const unsigned short* __restrict__ Vh, unsigned short* __restrict__ VhT)
{
    __shared__ unsigned short Ts[64 * 72];
    int bh = blockIdx.y;
    int t0 = blockIdx.x * 64;
    const unsigned short* src = Vh + (size_t)bh * 2048 * 64;
    unsigned short* dst = VhT + (size_t)bh * 2048 * 64;
    int tid = threadIdx.x;
    int c = tid & 7, r = tid >> 3;
    for (int i = 0; i < 64; i += 32)
        *(uint4*)&Ts[(r + i) * 72 + c * 8] =
            *(const uint4*)&src[(size_t)(t0 + r + i) * 64 + c * 8];
    __syncthreads();
    for (int i = 0; i < 64; i += 32) {
        union { unsigned short s[8]; uint4 v; } u;
        for (int j = 0; j < 8; j++) u.s[j] = Ts[(c * 8 + j) * 72 + (r + i)];
        *(uint4*)&dst[(size_t)(r + i) * 2048 + t0 + c * 8] = u.v;
    }
}

// ---------------------------------------------------------------------------
// GEMM: out = A[4096][1024] * BT[1024][1024]^T + bias, f32 accum via bf16 MFMA.
// A: f32 (a_is_f32=1, d_in) or bf16 (ws). BT: bf16 ws. bias: f32 d_in.
// mode 0: f32 row-major out [4096][1024] (d_out).
// mode 1: bf16 scatter to [b(2)][h(16)][t(2048)][d(64)], scaled (Q: 1/8).
// Tile 128x128, BK=32, 4 waves each 64x64 (4x4 of 16x16x32 MFMA).
// ---------------------------------------------------------------------------
__global__ __launch_bounds__(256) void gemm_bias(
    const void* __restrict__ Av, const unsigned short* __restrict__ BT,
    const float* __restrict__ bias, void* __restrict__ outv,
    int a_is_f32, int mode, float scale)
{
    const int K = 1024, N = 1024;
    __shared__ unsigned short As[128 * 40];
    __shared__ unsigned short Bs[128 * 40];
    int tid = threadIdx.x;
    int m0 = blockIdx.x * 128, n0 = blockIdx.y * 128;
    int lane = tid & 63, wave = tid >> 6;
    int lm = lane & 15, quad = lane >> 4;
    int wm = (wave >> 1) * 64, wn = (wave & 1) * 64;
    int sr = tid >> 2, skq = (tid & 3) * 8;

    f32x4 acc[4][4];
    for (int i = 0; i < 4; i++)
        for (int j = 0; j < 4; j++)
            for (int r = 0; r < 4; r++) acc[i][j][r] = 0.0f;

    for (int kb = 0; kb < K; kb += 32) {
        if (a_is_f32) {
            const float* A = (const float*)Av;
            for (int hh = 0; hh < 2; hh++) {
                const float* src = &A[(size_t)(m0 + sr + hh * 64) * K + kb + skq];
                float4 x0 = *(const float4*)src;
                float4 x1 = *(const float4*)(src + 4);
                unsigned short* d = &As[(sr + hh * 64) * 40 + skq];
                d[0] = f2bf(x0.x); d[1] = f2bf(x0.y); d[2] = f2bf(x0.z); d[3] = f2bf(x0.w);
                d[4] = f2bf(x1.x); d[5] = f2bf(x1.y); d[6] = f2bf(x1.z); d[7] = f2bf(x1.w);
            }
        } else {
            const unsigned short* A = (const unsigned short*)Av;
            *(uint4*)&As[sr * 40 + skq]        = *(const uint4*)&A[(size_t)(m0 + sr) * K + kb + skq];
            *(uint4*)&As[(sr + 64) * 40 + skq] = *(const uint4*)&A[(size_t)(m0 + sr + 64) * K + kb + skq];
        }
        *(uint4*)&Bs[sr * 40 + skq]        = *(const uint4*)&BT[(size_t)(n0 + sr) * K + kb + skq];
        *(uint4*)&Bs[(sr + 64) * 40 + skq] = *(const uint4*)&BT[(size_t)(n0 + sr + 64) * K + kb + skq];
        __syncthreads();
        short8 a[4], b[4];
        for (int i = 0; i < 4; i++)
            a[i] = *(const short8*)&As[(wm + i * 16 + lm) * 40 + quad * 8];
        for (int j = 0; j < 4; j++)
            b[j] = *(const short8*)&Bs[(wn + j * 16 + lm) * 40 + quad * 8];
        for (int i = 0; i < 4; i++)
            for (int j = 0; j < 4; j++)
                acc[i][j] = __builtin_amdgcn_mfma_f32_16x16x32_bf16(a[i], b[j], acc[i][j], 0, 0, 0);
        __syncthreads();
    }

    for (int j = 0; j < 4; j++) {
        int col = n0 + wn + j * 16 + lm;
        float bv = bias[col];
        for (int i = 0; i < 4; i++) {
            int rowb = m0 + wm + i * 16 + quad * 4;
            for (int r = 0; r < 4; r++) {
                int row = rowb + r;
                float vv = (acc[i][j][r] + bv) * scale;
                if (mode == 0) {
                    ((float*)outv)[(size_t)row * N + col] = vv;
                } else {
                    int h = col >> 6, d = col & 63;
                    int bb = row >> 11, t = row & 2047;
                    ((unsigned short*)outv)[(((size_t)(bb * 16 + h)) * 2048 + t) * 64 + d] = f2bf(vv);
                }
            }
        }
    }
}

// ---------------------------------------------------------------------------
// Flash attention: one block per (bh, 64 q rows); 4 waves x 16 rows each.
// K-tiles of 64 keys. QK^T and PV via mfma_f32_16x16x32_bf16.
// Qh pre-scaled by 1/sqrt(64) in projection. Online softmax per q-row.
// All-finite arithmetic: m init = -3e38f, no INFINITY anywhere.
// ---------------------------------------------------------------------------
__global__ __launch_bounds__(256) void attn_kernel(
    const unsigned short* __restrict__ Qh, const unsigned short* __restrict__ Kh,
    const unsigned short* __restrict__ VhT, unsigned short* __restrict__ X)
{
    __shared__ unsigned short Ks[64 * 72];
    __shared__ unsigned short Vt[64 * 72];
    __shared__ unsigned short Ps[4 * 16 * 72];

    int tid = threadIdx.x;
    int qb = blockIdx.x & 31, bh = blockIdx.x >> 5;
    int b = bh >> 4, h = bh & 15;
    int lane = tid & 63, wave = tid >> 6;
    int lm = lane & 15, quad = lane >> 4;

    // Q fragments (A-operand: m=lane&15 row, k=quad*8+j within head dim)
    int qrow = qb * 64 + wave * 16 + lm;
    const unsigned short* qptr = Qh + ((size_t)bh * 2048 + qrow) * 64;
    short8 qf0 = *(const short8*)&qptr[quad * 8];
    short8 qf1 = *(const short8*)&qptr[32 + quad * 8];

    f32x4 o[4];
    float m_r[4], l_r[4];
    for (int d = 0; d < 4; d++)
        for (int r = 0; r < 4; r++) o[d][r] = 0.0f;
    for (int r = 0; r < 4; r++) { m_r[r] = -3.0e38f; l_r[r] = 0.0f; }

    int sc = tid & 7, sr2 = tid >> 3;  // staging: chunk, row 0..31
    const unsigned short* Kbase = Kh + (size_t)bh * 2048 * 64;
    const unsigned short* Vbase = VhT + (size_t)bh * 64 * 2048;
    unsigned short* Pw = Ps + wave * 16 * 72;

    for (int kt = 0; kt < 32; kt++) {
        int k0 = kt * 64;
        *(uint4*)&Ks[sr2 * 72 + sc * 8]        = *(const uint4*)&Kbase[(size_t)(k0 + sr2) * 64 + sc * 8];
        *(uint4*)&Ks[(sr2 + 32) * 72 + sc * 8] = *(const uint4*)&Kbase[(size_t)(k0 + sr2 + 32) * 64 + sc * 8];
        *(uint4*)&Vt[sr2 * 72 + sc * 8]        = *(const uint4*)&Vbase[(size_t)sr2 * 2048 + k0 + sc * 8];
        *(uint4*)&Vt[(sr2 + 32) * 72 + sc * 8] = *(const uint4*)&Vbase[(size_t)(sr2 + 32) * 2048 + k0 + sc * 8];
        __syncthreads();

        // S = Q * K^T  (keys are B-operand n; head-dim is contraction)
        f32x4 s[4];
        for (int n = 0; n < 4; n++) {
            short8 kb0 = *(const short8*)&Ks[(n * 16 + lm) * 72 + quad * 8];
            short8 kb1 = *(const short8*)&Ks[(n * 16 + lm) * 72 + 32 + quad * 8];
            f32x4 z;
            z[0] = z[1] = z[2] = z[3] = 0.0f;
            z = __builtin_amdgcn_mfma_f32_16x16x32_bf16(qf0, kb0, z, 0, 0, 0);
            z = __builtin_amdgcn_mfma_f32_16x16x32_bf16(qf1, kb1, z, 0, 0, 0);
            s[n] = z;
        }

        // online softmax: row = quad*4 + r, cols spread over 16 lanes x 4 subtiles
        float mnew[4], alpha[4];
        for (int r = 0; r < 4; r++) {
            float t = fmaxf(fmaxf(s[0][r], s[1][r]), fmaxf(s[2][r], s[3][r]));
            for (int off = 1; off < 16; off <<= 1) t = fmaxf(t, __shfl_xor(t, off));
            mnew[r] = fmaxf(m_r[r], t);
            alpha[r] = __expf(m_r[r] - mnew[r]);
            m_r[r] = mnew[r];
        }
        for (int r = 0; r < 4; r++) {
            float su = 0.0f;
            for (int n = 0; n < 4; n++) {
                float p = __expf(s[n][r] - mnew[r]);
                s[n][r] = p;
                su += p;
            }
            for (int off = 1; off < 16; off <<= 1) su += __shfl_xor(su, off);
            l_r[r] = l_r[r] * alpha[r] + su;
        }
        for (int d = 0; d < 4; d++)
            for (int r = 0; r < 4; r++) o[d][r] *= alpha[r];

        // P: C-layout -> A-operand layout via LDS, fenced both sides
        for (int n = 0; n < 4; n++)
            for (int r = 0; r < 4; r++)
                Pw[(quad * 4 + r) * 72 + n * 16 + lm] = f2bf(s[n][r]);
        __syncthreads();
        short8 pf0 = *(const short8*)&Pw[lm * 72 + quad * 8];
        short8 pf1 = *(const short8*)&Pw[lm * 72 + 32 + quad * 8];

        // O += P * V   (V^T staged: row d, key-contiguous)
        for (int d = 0; d < 4; d++) {
            short8 vb0 = *(const short8*)&Vt[(d * 16 + lm) * 72 + quad * 8];
            short8 vb1 = *(const short8*)&Vt[(d * 16 + lm) * 72 + 32 + quad * 8];
            o[d] = __builtin_amdgcn_mfma_f32_16x16x32_bf16(pf0, vb0, o[d], 0, 0, 0);
            o[d] = __builtin_amdgcn_mfma_f32_16x16x32_bf16(pf1, vb1, o[d], 0, 0, 0);
        }
        __syncthreads();
    }

    for (int d = 0; d < 4; d++)
        for (int r = 0; r < 4; r++) {
            int row = qb * 64 + wave * 16 + quad * 4 + r;
            float vv = o[d][r] / fmaxf(l_r[r], 1e-30f);
            X[((size_t)b * 2048 + row) * 1024 + h * 64 + d * 16 + lm] = f2bf(vv);
        }
}

// ---------------------------------------------------------------------------
extern "C" void kernel_launch(void* const* d_in, const int* in_sizes, int n_in,
                              void* d_out, int out_size, void* d_ws, size_t ws_size,
                              hipStream_t stream)
{
    const float* q  = (const float*)d_in[0];
    const float* k  = (const float*)d_in[1];
    const float* v  = (const float*)d_in[2];
    const float* Wq = (const float*)d_in[3];
    const float* bq = (const float*)d_in[4];
    const float* Wk = (const float*)d_in[5];
    const float* bk = (const float*)d_in[6];
    const float* Wv = (const float*)d_in[7];
    const float* bv = (const float*)d_in[8];
    const float* Wo = (const float*)d_in[9];
    const float* bo = (const float*)d_in[10];

    unsigned short* ws  = (unsigned short*)d_ws;
    unsigned short* WqT = ws;                      // 1M bf16 elems each
    unsigned short* WkT = ws + (1u << 20);
    unsigned short* WvT = ws + 2u * (1u << 20);
    unsigned short* WoT = ws + 3u * (1u << 20);
    unsigned short* Qh  = ws + 4u * (1u << 20);    // 4M bf16 elems each
    unsigned short* Kh  = ws + 8u * (1u << 20);
    unsigned short* Vh  = ws + 12u * (1u << 20);
    unsigned short* VhT = ws + 16u * (1u << 20);
    unsigned short* X   = Vh;                      // Vh dead after transpose_v
                                                   // total ws: 40 MB

    transpose_w<<<dim3(16, 16, 4), 256, 0, stream>>>(Wq, Wk, Wv, Wo, WqT, WkT, WvT, WoT);
    gemm_bias<<<dim3(32, 8), 256, 0, stream>>>(q, WqT, bq, Qh, 1, 1, 0.125f);  // 1/sqrt(64)
    gemm_bias<<<dim3(32, 8), 256, 0, stream>>>(k, WkT, bk, Kh, 1, 1, 1.0f);
    gemm_bias<<<dim3(32, 8), 256, 0, stream>>>(v, WvT, bv, Vh, 1, 1, 1.0f);
    transpose_v<<<dim3(32, 32), 256, 0, stream>>>(Vh, VhT);
    attn_kernel<<<dim3(1024), 256, 0, stream>>>(Qh, Kh, VhT, X);
    gemm_bias<<<dim3(32, 8), 256, 0, stream>>>(X, WoT, bo, d_out, 0, 0, 1.0f);
}